// Round 2
// baseline (896.945 us; speedup 1.0000x reference)
//
#include <hip/hip_runtime.h>
#include <hip/hip_bf16.h>

// Problem constants (B=1)
#define S_LEN 4096
#define D_MODEL 512
#define NHEAD 8
#define HD 64

typedef short bf16x8 __attribute__((ext_vector_type(8)));   // MFMA A/B frag: 8 bf16
typedef short short4v __attribute__((ext_vector_type(4)));
typedef float f32x4 __attribute__((ext_vector_type(4)));    // MFMA C/D frag

static __device__ __forceinline__ short f2bf(float f) {
    __hip_bfloat16 h = __float2bfloat16(f);
    return *reinterpret_cast<short*>(&h);
}

// LDS index helpers with XOR bank swizzle (G4: 128B/64B rows are 16/8-way conflicts unswizzled).
// 64-short (128 B) rows:
static __device__ __forceinline__ int idx64(int row, int col) {
    return row * 64 + (col ^ ((row & 7) << 3));
}
// 32-short (64 B) rows:
static __device__ __forceinline__ int idx32(int row, int col) {
    return row * 32 + (col ^ ((row & 3) << 3));
}

// ---------------------------------------------------------------------------
// GEMM: C[M=4096][N=512] = A[4096][512] @ W[512][512] + bias
// ABF16: 0 = A fp32 (convert to bf16 while staging), 1 = A already bf16
// OMODE: 0 = bf16 out [M][N]; 1 = bf16 out TRANSPOSED [N][M] (for V); 2 = fp32 out [M][N]
// Block: 256 thr (4 waves 2x2), tile 128x128, BK=32 (one 16x16x32 MFMA K-step).
// ---------------------------------------------------------------------------
template<int ABF16, int OMODE>
__global__ __launch_bounds__(256)
void gemm512(const void* __restrict__ Ap, const float* __restrict__ Wp,
             const float* __restrict__ bias, void* __restrict__ outp)
{
    __shared__ short Asm[128 * 32];   // [m][k], swizzled
    __shared__ short Bsm[128 * 32];   // [n][k], swizzled (W transposed during staging)

    const int t = threadIdx.x;
    const int m0 = blockIdx.x * 128, n0 = blockIdx.y * 128;
    const int wv = t >> 6, l = t & 63, lr = l & 15, lg = l >> 4;
    const int wr = (wv >> 1) * 64, wc = (wv & 1) * 64;   // wave's 64x64 sub-tile

    f32x4 acc[4][4];
#pragma unroll
    for (int i = 0; i < 4; i++)
#pragma unroll
        for (int j = 0; j < 4; j++)
#pragma unroll
            for (int r = 0; r < 4; r++) acc[i][j][r] = 0.f;

    for (int k0 = 0; k0 < 512; k0 += 32) {
        __syncthreads();
        // ---- stage A tile [128][32]
        {
            const int r = t >> 1, c0 = (t & 1) * 16;
            if (ABF16) {
                const uint4* src = (const uint4*)((const short*)Ap + (size_t)(m0 + r) * 512 + k0 + c0);
                uint4 v0 = src[0], v1 = src[1];
                *(uint4*)&Asm[idx32(r, c0)]     = v0;
                *(uint4*)&Asm[idx32(r, c0 + 8)] = v1;
            } else {
                const float4* src = (const float4*)((const float*)Ap + (size_t)(m0 + r) * 512 + k0 + c0);
                float4 f0 = src[0], f1 = src[1], f2 = src[2], f3 = src[3];
                bf16x8 p0, p1;
                p0[0] = f2bf(f0.x); p0[1] = f2bf(f0.y); p0[2] = f2bf(f0.z); p0[3] = f2bf(f0.w);
                p0[4] = f2bf(f1.x); p0[5] = f2bf(f1.y); p0[6] = f2bf(f1.z); p0[7] = f2bf(f1.w);
                p1[0] = f2bf(f2.x); p1[1] = f2bf(f2.y); p1[2] = f2bf(f2.z); p1[3] = f2bf(f2.w);
                p1[4] = f2bf(f3.x); p1[5] = f2bf(f3.y); p1[6] = f2bf(f3.z); p1[7] = f2bf(f3.w);
                *(bf16x8*)&Asm[idx32(r, c0)]     = p0;
                *(bf16x8*)&Asm[idx32(r, c0 + 8)] = p1;
            }
        }
        // ---- stage B tile: W[k0..k0+31][n0..n0+127] -> Bsm[n][k] (transpose)
        {
            const int n = t & 127, kh = (t >> 7) * 16;
            const float* wp = Wp + (size_t)(k0 + kh) * 512 + n0 + n;
#pragma unroll
            for (int i = 0; i < 16; i++)
                Bsm[idx32(n, kh + i)] = f2bf(wp[(size_t)i * 512]);
        }
        __syncthreads();

        bf16x8 a[4], b[4];
#pragma unroll
        for (int mi = 0; mi < 4; mi++)
            a[mi] = *(const bf16x8*)&Asm[idx32(wr + mi * 16 + lr, lg * 8)];
#pragma unroll
        for (int ni = 0; ni < 4; ni++)
            b[ni] = *(const bf16x8*)&Bsm[idx32(wc + ni * 16 + lr, lg * 8)];
#pragma unroll
        for (int mi = 0; mi < 4; mi++)
#pragma unroll
            for (int ni = 0; ni < 4; ni++)
                acc[mi][ni] = __builtin_amdgcn_mfma_f32_16x16x32_bf16(a[mi], b[ni], acc[mi][ni], 0, 0, 0);
    }

    // ---- epilogue: C/D layout col=lane&15, row=(lane>>4)*4+reg (m89-verified)
#pragma unroll
    for (int ni = 0; ni < 4; ni++) {
        const int col = n0 + wc + ni * 16 + lr;
        const float bvv = bias[col];
#pragma unroll
        for (int mi = 0; mi < 4; mi++) {
            const int rbase = m0 + wr + mi * 16 + lg * 4;
            if (OMODE == 0) {
                short* o = (short*)outp;
#pragma unroll
                for (int r = 0; r < 4; r++)
                    o[(size_t)(rbase + r) * 512 + col] = f2bf(acc[mi][ni][r] + bvv);
            } else if (OMODE == 1) {
                short* o = (short*)outp;  // [512][4096] = V^T
                short4v pk;
#pragma unroll
                for (int r = 0; r < 4; r++) pk[r] = f2bf(acc[mi][ni][r] + bvv);
                *(short4v*)&o[(size_t)col * 4096 + rbase] = pk;
            } else {
                float* o = (float*)outp;
#pragma unroll
                for (int r = 0; r < 4; r++)
                    o[(size_t)(rbase + r) * 512 + col] = acc[mi][ni][r] + bvv;
            }
        }
    }
}

// ---------------------------------------------------------------------------
// Fused attention: one block = (head h, 64 query rows). 256 thr = 4 waves,
// wave w owns q-rows w*16..w*16+15 end-to-end.
// Pass 1: online rowmax/rowsum of exp over all keys. Pass 2: recompute scores
// (bitwise identical), write normalized weights fp32, accumulate PV in bf16 MFMA.
// ---------------------------------------------------------------------------
__global__ __launch_bounds__(256)
void attn_fused(const short* __restrict__ Qb, const short* __restrict__ Kb,
                const short* __restrict__ Vt, float* __restrict__ Wout,
                short* __restrict__ Mg)
{
    __shared__ short Qs[64 * 64];
    __shared__ short Ks[64 * 64];
    __shared__ short Vs[64 * 64];   // V^T tile: [d][key]
    __shared__ short Ps[64 * 64];   // probs tile (bf16) for PV A-operand

    const int t = threadIdx.x;
    const int h = blockIdx.y;
    const int q0 = blockIdx.x * 64;
    const int wv = t >> 6, l = t & 63, lr = l & 15, lg = l >> 4;

    // stage Q tile [64 q][64 d]
    {
        const int r = t >> 2, c0 = (t & 3) * 16;
        const uint4* src = (const uint4*)(Qb + (size_t)(q0 + r) * 512 + h * 64 + c0);
        uint4 v0 = src[0], v1 = src[1];
        *(uint4*)&Qs[idx64(r, c0)]     = v0;
        *(uint4*)&Qs[idx64(r, c0 + 8)] = v1;
    }
    __syncthreads();

    bf16x8 aq[2];   // this wave's 16 q-rows, d=0..31 and d=32..63
    aq[0] = *(const bf16x8*)&Qs[idx64(wv * 16 + lr, lg * 8)];
    aq[1] = *(const bf16x8*)&Qs[idx64(wv * 16 + lr, 32 + lg * 8)];

    float mrow[4], lden[4];
#pragma unroll
    for (int r = 0; r < 4; r++) { mrow[r] = -1e30f; lden[r] = 0.f; }

    // ---------------- pass 1: online max / sum(exp) ----------------
    for (int kt = 0; kt < 64; kt++) {
        __syncthreads();
        {
            const int r = t >> 2, c0 = (t & 3) * 16;
            const uint4* src = (const uint4*)(Kb + (size_t)(kt * 64 + r) * 512 + h * 64 + c0);
            uint4 v0 = src[0], v1 = src[1];
            *(uint4*)&Ks[idx64(r, c0)]     = v0;
            *(uint4*)&Ks[idx64(r, c0 + 8)] = v1;
        }
        __syncthreads();

        f32x4 s[4];
#pragma unroll
        for (int ni = 0; ni < 4; ni++)
#pragma unroll
            for (int r = 0; r < 4; r++) s[ni][r] = 0.f;
#pragma unroll
        for (int ks = 0; ks < 2; ks++) {
#pragma unroll
            for (int ni = 0; ni < 4; ni++) {
                bf16x8 bk = *(const bf16x8*)&Ks[idx64(ni * 16 + lr, ks * 32 + lg * 8)];
                s[ni] = __builtin_amdgcn_mfma_f32_16x16x32_bf16(aq[ks], bk, s[ni], 0, 0, 0);
            }
        }
#pragma unroll
        for (int ni = 0; ni < 4; ni++)
#pragma unroll
            for (int r = 0; r < 4; r++) s[ni][r] *= 0.125f;   // 1/sqrt(64)

#pragma unroll
        for (int r = 0; r < 4; r++) {
            float tm = fmaxf(fmaxf(s[0][r], s[1][r]), fmaxf(s[2][r], s[3][r]));
#pragma unroll
            for (int d = 1; d < 16; d <<= 1) tm = fmaxf(tm, __shfl_xor(tm, d));
            const float mn = fmaxf(mrow[r], tm);
            const float corr = __expf(mrow[r] - mn);
            float ps = __expf(s[0][r] - mn) + __expf(s[1][r] - mn)
                     + __expf(s[2][r] - mn) + __expf(s[3][r] - mn);
#pragma unroll
            for (int d = 1; d < 16; d <<= 1) ps += __shfl_xor(ps, d);
            lden[r] = lden[r] * corr + ps;
            mrow[r] = mn;
        }
    }
    float rinv[4];
#pragma unroll
    for (int r = 0; r < 4; r++) rinv[r] = 1.f / lden[r];

    // ---------------- pass 2: normalize, write weights, PV ----------------
    f32x4 o[4];
#pragma unroll
    for (int ni = 0; ni < 4; ni++)
#pragma unroll
        for (int r = 0; r < 4; r++) o[ni][r] = 0.f;

    for (int kt = 0; kt < 64; kt++) {
        __syncthreads();
        {
            const int r = t >> 2, c0 = (t & 3) * 16;
            const uint4* srck = (const uint4*)(Kb + (size_t)(kt * 64 + r) * 512 + h * 64 + c0);
            uint4 k0v = srck[0], k1v = srck[1];
            *(uint4*)&Ks[idx64(r, c0)]     = k0v;
            *(uint4*)&Ks[idx64(r, c0 + 8)] = k1v;
            const uint4* srcv = (const uint4*)(Vt + (size_t)(h * 64 + r) * 4096 + kt * 64 + c0);
            uint4 v0 = srcv[0], v1 = srcv[1];
            *(uint4*)&Vs[idx64(r, c0)]     = v0;
            *(uint4*)&Vs[idx64(r, c0 + 8)] = v1;
        }
        __syncthreads();

        f32x4 s[4];
#pragma unroll
        for (int ni = 0; ni < 4; ni++)
#pragma unroll
            for (int r = 0; r < 4; r++) s[ni][r] = 0.f;
#pragma unroll
        for (int ks = 0; ks < 2; ks++) {
#pragma unroll
            for (int ni = 0; ni < 4; ni++) {
                bf16x8 bk = *(const bf16x8*)&Ks[idx64(ni * 16 + lr, ks * 32 + lg * 8)];
                s[ni] = __builtin_amdgcn_mfma_f32_16x16x32_bf16(aq[ks], bk, s[ni], 0, 0, 0);
            }
        }
        // normalized probs: recompute is bitwise-identical to pass 1, so s - m <= 0
#pragma unroll
        for (int ni = 0; ni < 4; ni++) {
#pragma unroll
            for (int r = 0; r < 4; r++) {
                const float p = __expf(s[ni][r] * 0.125f - mrow[r]) * rinv[r];
                const int qrow = q0 + wv * 16 + lg * 4 + r;
                Wout[((size_t)h * S_LEN + qrow) * S_LEN + kt * 64 + ni * 16 + lr] = p;
                Ps[idx64(wv * 16 + lg * 4 + r, ni * 16 + lr)] = f2bf(p);
            }
        }
        __syncthreads();
        // PV: O[16q][64d] += P[16q][64key] @ V[64key][64d]
#pragma unroll
        for (int ks = 0; ks < 2; ks++) {
            bf16x8 ap = *(const bf16x8*)&Ps[idx64(wv * 16 + lr, ks * 32 + lg * 8)];
#pragma unroll
            for (int ni = 0; ni < 4; ni++) {
                bf16x8 bvf = *(const bf16x8*)&Vs[idx64(ni * 16 + lr, ks * 32 + lg * 8)];
                o[ni] = __builtin_amdgcn_mfma_f32_16x16x32_bf16(ap, bvf, o[ni], 0, 0, 0);
            }
        }
    }

    // merged layout [S][512], head h at cols h*64..
#pragma unroll
    for (int ni = 0; ni < 4; ni++)
#pragma unroll
        for (int r = 0; r < 4; r++) {
            const int qrow = q0 + wv * 16 + lg * 4 + r;
            Mg[(size_t)qrow * 512 + h * 64 + ni * 16 + lr] = f2bf(o[ni][r]);
        }
}

// ---------------------------------------------------------------------------
extern "C" void kernel_launch(void* const* d_in, const int* in_sizes, int n_in,
                              void* d_out, int out_size, void* d_ws, size_t ws_size,
                              hipStream_t stream)
{
    const float* x1 = (const float*)d_in[0];
    const float* x2 = (const float*)d_in[1];
    const float* x3 = (const float*)d_in[2];
    const float* Wq = (const float*)d_in[3];
    const float* bq = (const float*)d_in[4];
    const float* Wk = (const float*)d_in[5];
    const float* bk = (const float*)d_in[6];
    const float* Wv = (const float*)d_in[7];
    const float* bv = (const float*)d_in[8];
    const float* Wo = (const float*)d_in[9];
    const float* bo = (const float*)d_in[10];

    float* out0 = (float*)d_out;                       // [4096][512]
    float* wout = out0 + (size_t)S_LEN * D_MODEL;      // [8][4096][4096]

    short* Qb = (short*)d_ws;                          // bf16 [4096][512]
    short* Kb = Qb + (size_t)S_LEN * D_MODEL;          // bf16 [4096][512]
    short* Vt = Kb + (size_t)S_LEN * D_MODEL;          // bf16 [512][4096] (V transposed)
    short* Mg = Vt + (size_t)S_LEN * D_MODEL;          // bf16 [4096][512] (attn merged)

    dim3 blk(256), grd(32, 4);
    gemm512<0, 0><<<grd, blk, 0, stream>>>((const void*)x1, Wq, bq, (void*)Qb);
    gemm512<0, 0><<<grd, blk, 0, stream>>>((const void*)x2, Wk, bk, (void*)Kb);
    gemm512<0, 1><<<grd, blk, 0, stream>>>((const void*)x3, Wv, bv, (void*)Vt);
    attn_fused<<<dim3(64, 8), blk, 0, stream>>>(Qb, Kb, Vt, wout, Mg);
    gemm512<1, 2><<<grd, blk, 0, stream>>>((const void*)Mg, Wo, bo, (void*)out0);
}